// Round 8
// baseline (365.638 us; speedup 1.0000x reference)
//
#include <hip/hip_runtime.h>
#include <cstdint>

#define SEQ 512
#define BATCH 2048
#define HID 50
#define BB 8              // batches per block
#define NTHR 1024         // 16 waves: 0-7 = L1 group, 8-15 = L2 group
#define NBLK (BATCH / BB) // 256 blocks -> 1 per CU
#define NT 13             // gate-row tiles of 16 (200 -> 208, permuted rows)
#define S1H 80            // u1 stride halves: 40 dwords === 8 (mod 32)
#define S2H 144           // u2 stride halves: 72 dwords === 8 (mod 32)
#define NSTEP 516         // SEQ+4, multiple of 4 (4-phase slot unroll)

typedef _Float16 f16;
typedef _Float16 v8h __attribute__((ext_vector_type(8)));
typedef float    v4f __attribute__((ext_vector_type(4)));

#if __has_builtin(__builtin_amdgcn_exp2f)
#define EXP2F(x) __builtin_amdgcn_exp2f(x)
#else
#define EXP2F(x) exp2f(x)
#endif
#define RCPF(x) __builtin_amdgcn_rcpf(x)
#define LOG2E 1.44269504f
#define MFMA(A,B,C) __builtin_amdgcn_mfma_f32_16x16x32_f16(A, B, C, 0, 0, 0)

// R8 = R7 (332.7us / 292.7 best) + latency cuts on the laggard chains:
//  - L2 retimed to t=s-2 with u2 as FOUR slots (mod-4) and a padded K-layout:
//    u2 row = [relu_h1 k=0..49 | zeros 50..63 | h2 k=64..113 | zeros..127].
//    relu half (C0,C1) of the NEXT superstep's operand is final one full
//    superstep early -> PREFETCHED into registers during superstep s-1
//    (c0f/c1f live across the barrier). Only C2,C3 (h2 half, written s-1)
//    is read post-barrier; its latency overlaps the prefetched MFMAs.
//    Slot timing: L2@s reads slot s&3; L1@s writes relu -> slot (s+2)&3;
//    L2@s writes h2 -> slot (s+1)&3 (offsets 64.., disjoint from prefetch).
//  - split-accumulator MFMA chains (both layers): a0=bias+K-half-1,
//    a0b=0+K-half-2, m = sel(a0,a1)+sel(a0b,a1b). Serial MFMA depth 4->2
//    (L2) and 2->1 (L1, the true recurrence path).
//  - loop unrolled x4 so slot indices are compile-time literals.
// Pipeline: L1(t=s) | L2(t=s-2) | fc-reduce(t=s-3) -> 516 supersteps.
// Carried: bias in MFMA C-in, merged-rcp update, raw fcw partials + wave-6
// reduce, x in LDS (xl), out in LDS (outb), setprio on heavy waves.
// Row permutation (validated): tile tt, in-tile row rho -> orig W row
// (rho%4)*50 + tt*4 + rho/4.  C layout (col=lane&15, row=(lane>>4)*4+reg).
// Gate rows pre-scaled (i,f,o: -log2e; g: +2log2e) -> raw v_exp_f32.

__global__ __launch_bounds__(NTHR, 1) void lstm2_fused(
    const float* __restrict__ x,
    const float* __restrict__ w_ih1, const float* __restrict__ w_hh1,
    const float* __restrict__ b_ih1, const float* __restrict__ b_hh1,
    const float* __restrict__ w_ih2, const float* __restrict__ w_hh2,
    const float* __restrict__ b_ih2, const float* __restrict__ b_hh2,
    const float* __restrict__ w_fc, const float* __restrict__ b_fc,
    float* __restrict__ out)
{
    __shared__ __align__(16) f16 u1h[2][BB * S1H];        // 2560 B
    __shared__ __align__(16) f16 u2h[4][BB * S2H];        // 9216 B (4 slots)
    __shared__ float fcw[2][8][64];                       // 4096 B raw FC partials
    __shared__ __align__(16) f16 xl[SEQ][BB * 4];         // 32 KB: whole x slice
    __shared__ __align__(16) float outb[SEQ][BB];         // 16 KB: out buffer
    // total 65024 B

    const int tid  = threadIdx.x;
    const int wv   = tid >> 6;        // 0..15
    const int lane = tid & 63;
    const int mb   = lane & 15;       // A-row-in-tile | C col
    const int q    = lane >> 4;       // quad
    const int bbase = blockIdx.x * BB;

    const bool grpB = (wv >= 8);              // waves 8-15: L2
    const int  wa   = grpB ? (15 - wv) : wv;  // 0..7
    const bool heavy = (wa < NT - 8);         // 2-tile wave

    const bool hiHalf = (mb >= 8);
    const int  myt    = hiHalf ? (wa + 8) : wa;
    const int  u_me   = myt * 4 + q;
    const bool valid_upd = (myt < NT) && (u_me < HID);
    const int  b_me   = mb & 7;       // batch: B-col AND update identity

    const int   gidx = mb & 3;        // gate of this lane's A rows
    const float sc   = (gidx == 2) ? (2.0f * LOG2E) : (-LOG2E);

    // ---- weight-stationary A fragments (scaled, NO bias column) ----
    // L2 k-map matches padded u2 row: k<50 -> w_ih2; 64<=k<114 -> w_hh2.
    v8h Af[2][4];                     // [tile][ktile]; L1 uses kt 0..1, L2 kt 0..3
#pragma unroll
    for (int i = 0; i < 2; ++i) {
        const int tt = wa + 8 * i;
        const bool tv = (tt < NT);
        const int ru = tt * 4 + (mb >> 2);
        const bool rv = tv && (ru < HID);
        const int R = gidx * HID + ru;       // original gate-major W row
        if (!grpB) {
#pragma unroll
            for (int kt = 0; kt < 2; ++kt) {
                v8h f;
#pragma unroll
                for (int j = 0; j < 8; ++j) {
                    const int kk = kt * 32 + q * 8 + j;
                    float v = 0.0f;
                    if (rv) {
                        if (kk < 4) v = w_ih1[R * 4 + kk];
                        else if (kk < 54) v = w_hh1[R * HID + (kk - 4)];
                    }
                    f[j] = (f16)(v * sc);
                }
                Af[i][kt] = f;
            }
        } else {
#pragma unroll
            for (int kt = 0; kt < 4; ++kt) {
                v8h f;
#pragma unroll
                for (int j = 0; j < 8; ++j) {
                    const int kk = kt * 32 + q * 8 + j;
                    float v = 0.0f;
                    if (rv) {
                        if (kk < HID) v = w_ih2[R * HID + kk];
                        else if (kk >= 64 && kk < 64 + HID) v = w_hh2[R * HID + (kk - 64)];
                    }
                    f[j] = (f16)(v * sc);
                }
                Af[i][kt] = f;
            }
        }
    }

    // ---- bias accumulators (C-in): reg r = gate r, unit = tile*4+q ----
    v4f bias0 = {0.f, 0.f, 0.f, 0.f}, bias1 = {0.f, 0.f, 0.f, 0.f};
#pragma unroll
    for (int r = 0; r < 4; ++r) {
        const float scr = (r == 2) ? (2.0f * LOG2E) : (-LOG2E);
        const int u0 = wa * 4 + q;
        const int u1t = (wa + 8) * 4 + q;
        const float* bi = grpB ? b_ih2 : b_ih1;
        const float* bh = grpB ? b_hh2 : b_hh1;
        if (u0 < HID) bias0[r] = (bi[r * HID + u0] + bh[r * HID + u0]) * scr;
        if ((wa + 8) < NT && u1t < HID)
            bias1[r] = (bi[r * HID + u1t] + bh[r * HID + u1t]) * scr;
    }
    const float wfc_me = (grpB && valid_upd) ? w_fc[u_me] : 0.0f;
    const float bfc = b_fc[0];
    float c_me = 0.0f;                // L1 cell (waves 0-7) / L2 cell (waves 8-15)
    const v4f zf = {0.f, 0.f, 0.f, 0.f};

    // ---- LDS init + x preload ----
    for (int idx = tid; idx < 2 * BB * S1H; idx += NTHR) ((f16*)u1h)[idx] = (f16)0.0f;
    for (int idx = tid; idx < 4 * BB * S2H; idx += NTHR) ((f16*)u2h)[idx] = (f16)0.0f;
    ((float*)fcw)[tid] = 0.0f;        // 2*8*64 = 1024 == NTHR
    for (int i = tid; i < SEQ * BB; i += NTHR) {   // 4 iters, coalesced
        const int t = i >> 3, b = i & 7;
        const float4 v = *reinterpret_cast<const float4*>(
            x + ((size_t)t * BATCH + bbase + b) * 4);
        f16 p[4] = {(f16)v.x, (f16)v.y, (f16)v.z, (f16)v.w};
        *reinterpret_cast<uint2*>(&xl[t][b * 4]) = *reinterpret_cast<uint2*>(p);
    }
    __syncthreads();
    if (tid < BB) {   // x(0) -> u1 parity 0
        *reinterpret_cast<uint2*>(&u1h[0][tid * S1H]) =
            *reinterpret_cast<const uint2*>(&xl[0][tid * 4]);
    }
    __syncthreads();

    // ---- static wave priority: heavy (2-tile) waves preferred (T5) ----
    if (heavy) __builtin_amdgcn_s_setprio(1);

    // ---- per-lane LDS offsets ----
    const int off_rd1 = b_me * S1H + q * 8;        // L1 B-read base
    const int off_rd2 = b_me * S2H + q * 8;        // L2 C-read base
    const int off_w_h1   = b_me * S1H + 4 + u_me;  // h1 -> u1
    const int off_w_relu = b_me * S2H + u_me;      // relu_h1 -> u2 (k=0..49)
    const int off_w_h2   = b_me * S2H + 64 + u_me; // h2 -> u2 (k=64..113)

    // ---- cross-barrier prefetch registers (L2 relu half) ----
    v8h c0f = {}; v8h c1f = {};

    // ---- superstep body; s runtime, ph literal (slot indices fold) ----
    auto body = [&](int s, int ph) __attribute__((always_inline)) {
        const int pr = ph & 1, pn = pr ^ 1;
        if (!grpB) {
            // ---------- L1 gates(t=s) ----------
            const f16* u1r = &u1h[pr][off_rd1];
            const v8h B0 = *reinterpret_cast<const v8h*>(u1r);
            const v8h B1 = *reinterpret_cast<const v8h*>(u1r + 32);
            v4f a0  = MFMA(Af[0][0], B0, bias0);   // split-acc: 1-deep chains
            v4f a0b = MFMA(Af[0][1], B1, zf);
            v4f m;
            if (heavy) {
                v4f a1  = MFMA(Af[1][0], B0, bias1);
                v4f a1b = MFMA(Af[1][1], B1, zf);
                m = (hiHalf ? a1 : a0) + (hiHalf ? a1b : a0b);
            } else {
                m = a0 + a0b;
            }
            const float A  = 1.0f + EXP2F(m[0]);
            const float F  = 1.0f + EXP2F(m[1]);
            const float Bv = 1.0f + EXP2F(m[2]);
            const float C  = 1.0f + EXP2F(m[3]);
            const float AB = A * Bv;
            c_me = (c_me * AB + (Bv - 2.0f) * F) * RCPF(F * AB);
            const float D = 1.0f + EXP2F(c_me * (2.0f * LOG2E));
            const float h1v = (D - 2.0f) * RCPF(C * D);
            if (valid_upd) {
                u1h[pn][off_w_h1] = (f16)h1v;
                u2h[(ph + 2) & 3][off_w_relu] = (f16)fmaxf(h1v, 0.0f);
            }
            // ---------- out reduce+store for t=s-3 (light wave 6) ----------
            if (wv == 6 && s >= 3 && s < SEQ + 3) {
                float v = 0.0f;
#pragma unroll
                for (int k2 = 0; k2 < 8; ++k2) v += fcw[pn][k2][lane];
                v += __shfl_xor(v, 8);     // merge lo/hi tile halves (same batch)
                v += __shfl_xor(v, 16);    // merge quads
                v += __shfl_xor(v, 32);
                if (lane < BB) outb[s - 3][lane] = v + bfc;
            }
        } else {
            // ---------- x(s+1) staging: LDS -> LDS (light wave 8) ----------
            if (wv == 8 && lane < BB) {
                const int tn = (s + 1 < SEQ) ? s + 1 : SEQ - 1;
                *reinterpret_cast<uint2*>(&u1h[pn][lane * S1H]) =
                    *reinterpret_cast<const uint2*>(&xl[tn][lane * 4]);
            }
            // ---------- L2 gates(t=s-2): C0/C1 prefetched, C2/C3 fresh ----------
            const f16* u2r = &u2h[ph][off_rd2];
            const v8h C2 = *reinterpret_cast<const v8h*>(u2r + 64);
            const v8h C3 = *reinterpret_cast<const v8h*>(u2r + 96);
            v4f a0 = MFMA(Af[0][0], c0f, bias0);   // starts immediately (regs)
            a0 = MFMA(Af[0][1], c1f, a0);
            v4f a0b = MFMA(Af[0][2], C2, zf);      // waits only on C2/C3 read
            a0b = MFMA(Af[0][3], C3, a0b);
            v4f m;
            if (heavy) {
                v4f a1 = MFMA(Af[1][0], c0f, bias1);
                a1 = MFMA(Af[1][1], c1f, a1);
                v4f a1b = MFMA(Af[1][2], C2, zf);
                a1b = MFMA(Af[1][3], C3, a1b);
                m = (hiHalf ? a1 : a0) + (hiHalf ? a1b : a0b);
            } else {
                m = a0 + a0b;
            }
            // prefetch relu half for NEXT superstep (slot (ph+1): relu written
            // at s-1, final; h2 region 64.. being written now is DISJOINT)
            {
                const f16* u2p = &u2h[(ph + 1) & 3][off_rd2];
                c0f = *reinterpret_cast<const v8h*>(u2p);
                c1f = *reinterpret_cast<const v8h*>(u2p + 32);
            }
            const float A  = 1.0f + EXP2F(m[0]);
            const float F  = 1.0f + EXP2F(m[1]);
            const float Bv = 1.0f + EXP2F(m[2]);
            const float C  = 1.0f + EXP2F(m[3]);
            const float AB = A * Bv;
            const float cn = (c_me * AB + (Bv - 2.0f) * F) * RCPF(F * AB);
            const float D = 1.0f + EXP2F(cn * (2.0f * LOG2E));
            const float h2v = (D - 2.0f) * RCPF(C * D);
            float p = 0.0f;
            if (s >= 2 && s < SEQ + 2) {        // t=s-2 in [0, 511]
                c_me = cn;
                if (valid_upd) u2h[(ph + 1) & 3][off_w_h2] = (f16)h2v;
                p = fmaxf(h2v, 0.0f) * wfc_me;  // wfc_me=0 on invalid lanes
            }
            fcw[pr][wv - 8][lane] = p;          // RAW partial, no shfl tail
        }
        __syncthreads();   // the ONE barrier per superstep
    };

    // ---- pipelined supersteps, unrolled x4 (slot indices literal) ----
#pragma unroll 1
    for (int s = 0; s < NSTEP; s += 4) {
        body(s, 0);
        body(s + 1, 1);
        body(s + 2, 2);
        body(s + 3, 3);
    }

    // ---- epilogue: flush outb -> global ----
    {
        const int i = tid;                 // SEQ*2 == 1024 == NTHR
        const int t = i >> 1, hb = (i & 1) * 4;
        *reinterpret_cast<float4*>(out + (size_t)t * BATCH + bbase + hb) =
            *reinterpret_cast<const float4*>(&outb[t][hb]);
    }
}

extern "C" void kernel_launch(void* const* d_in, const int* in_sizes, int n_in,
                              void* d_out, int out_size, void* d_ws, size_t ws_size,
                              hipStream_t stream) {
    const float* X    = (const float*)d_in[0];
    const float* Wih1 = (const float*)d_in[1];
    const float* Whh1 = (const float*)d_in[2];
    const float* Bih1 = (const float*)d_in[3];
    const float* Bhh1 = (const float*)d_in[4];
    const float* Wih2 = (const float*)d_in[5];
    const float* Whh2 = (const float*)d_in[6];
    const float* Bih2 = (const float*)d_in[7];
    const float* Bhh2 = (const float*)d_in[8];
    const float* Wfc  = (const float*)d_in[9];
    const float* Bfc  = (const float*)d_in[10];
    float* out = (float*)d_out;

    lstm2_fused<<<dim3(NBLK), dim3(NTHR), 0, stream>>>(
        X, Wih1, Whh1, Bih1, Bhh1, Wih2, Whh2, Bih2, Bhh2, Wfc, Bfc, out);
}

// Round 9
// 335.015 us; speedup vs baseline: 1.0914x; 1.0914x over previous
//
#include <hip/hip_runtime.h>
#include <cstdint>

#define SEQ 512
#define BATCH 2048
#define HID 50
#define BB 8              // batches per block
#define NTHR 1024         // 16 waves: 0-7 = L1 group, 8-15 = L2 group
#define NBLK (BATCH / BB) // 256 blocks -> 1 per CU
#define NT 13             // gate-row tiles of 16 (200 -> 208, permuted rows)
#define S1H 80            // u1 stride halves: 40 dwords === 8 (mod 32)
#define S2H 144           // u2 stride halves: 72 dwords === 8 (mod 32)
#define SL2 (BB * S2H)    // u2 slot stride (elements)
#define NSTEP 516         // SEQ+4, even (x2 unroll)

typedef _Float16 f16;
typedef _Float16 v8h __attribute__((ext_vector_type(8)));
typedef float    v4f __attribute__((ext_vector_type(4)));

#if __has_builtin(__builtin_amdgcn_exp2f)
#define EXP2F(x) __builtin_amdgcn_exp2f(x)
#else
#define EXP2F(x) exp2f(x)
#endif
#define RCPF(x) __builtin_amdgcn_rcpf(x)
#define LOG2E 1.44269504f
#define MFMA(A,B,C) __builtin_amdgcn_mfma_f32_16x16x32_f16(A, B, C, 0, 0, 0)

// R9 = R7 (332.7us / 292.7 best; VERIFIED) + ONE change: L2 retime+prefetch.
//  - L2 runs at t=s-2; u2 has FOUR slots (arithmetic slot index, x2 unroll
//    kept -> code size == R7, unlike R8's x4 bloat).
//  - u2 row K-layout: [relu_h1 k=0..49 | 0..63 | h2 k=64..113 | 0..127pad].
//    Slot timing: L2@s reads slot s&3 (h2 half post-barrier; relu half from
//    REGISTERS c0f/c1f prefetched during s-1 from slot (s+1)&3 -> operand is
//    final one full superstep early). L1@s writes relu -> slot (s+2)&3;
//    L2@s writes h2 -> slot (s+1)&3 (disjoint K-half from the prefetch read).
//  - MFMA chain order identical to R7 (bias->C0->C1->C2->C3 serial): results
//    bit-identical; first two operands are in regs at barrier exit so the
//    2 remaining ds_reads' latency hides under them.
// Pipeline: L1(t=s) | L2(t=s-2) | fc-reduce(t=s-3) -> 516 supersteps.
// Carried from R7: bias in MFMA C-in, merged-rcp update, raw fcw partials +
// wave-6 reduce, x in LDS (xl), out in LDS (outb), setprio on heavy waves,
// single-tile waves skip hiHalf selects.
// Row permutation (validated): tile tt, in-tile row rho -> orig W row
// (rho%4)*50 + tt*4 + rho/4.  C layout (col=lane&15, row=(lane>>4)*4+reg).
// Gate rows pre-scaled (i,f,o: -log2e; g: +2log2e) -> raw v_exp_f32.

__global__ __launch_bounds__(NTHR, 1) void lstm2_fused(
    const float* __restrict__ x,
    const float* __restrict__ w_ih1, const float* __restrict__ w_hh1,
    const float* __restrict__ b_ih1, const float* __restrict__ b_hh1,
    const float* __restrict__ w_ih2, const float* __restrict__ w_hh2,
    const float* __restrict__ b_ih2, const float* __restrict__ b_hh2,
    const float* __restrict__ w_fc, const float* __restrict__ b_fc,
    float* __restrict__ out)
{
    __shared__ __align__(16) f16 u1h[2][BB * S1H];        // 2560 B
    __shared__ __align__(16) f16 u2h[4][SL2];             // 9216 B (4 slots)
    __shared__ float fcw[2][8][64];                       // 4096 B raw FC partials
    __shared__ __align__(16) f16 xl[SEQ][BB * 4];         // 32 KB: whole x slice
    __shared__ __align__(16) float outb[SEQ][BB];         // 16 KB: out buffer
    // total 65024 B

    const int tid  = threadIdx.x;
    const int wv   = tid >> 6;        // 0..15
    const int lane = tid & 63;
    const int mb   = lane & 15;       // A-row-in-tile | C col
    const int q    = lane >> 4;       // quad
    const int bbase = blockIdx.x * BB;

    const bool grpB = (wv >= 8);              // waves 8-15: L2
    const int  wa   = grpB ? (15 - wv) : wv;  // 0..7
    const bool heavy = (wa < NT - 8);         // 2-tile wave

    const bool hiHalf = (mb >= 8);
    const int  myt    = hiHalf ? (wa + 8) : wa;
    const int  u_me   = myt * 4 + q;
    const bool valid_upd = (myt < NT) && (u_me < HID);
    const int  b_me   = mb & 7;       // batch: B-col AND update identity

    const int   gidx = mb & 3;        // gate of this lane's A rows
    const float sc   = (gidx == 2) ? (2.0f * LOG2E) : (-LOG2E);

    // ---- weight-stationary A fragments (scaled, NO bias column) ----
    // L2 k-map matches padded u2 row: k<50 -> w_ih2; 64<=k<114 -> w_hh2.
    v8h Af[2][4];                     // [tile][ktile]; L1 uses kt 0..1, L2 kt 0..3
#pragma unroll
    for (int i = 0; i < 2; ++i) {
        const int tt = wa + 8 * i;
        const bool tv = (tt < NT);
        const int ru = tt * 4 + (mb >> 2);
        const bool rv = tv && (ru < HID);
        const int R = gidx * HID + ru;       // original gate-major W row
        if (!grpB) {
#pragma unroll
            for (int kt = 0; kt < 2; ++kt) {
                v8h f;
#pragma unroll
                for (int j = 0; j < 8; ++j) {
                    const int kk = kt * 32 + q * 8 + j;
                    float v = 0.0f;
                    if (rv) {
                        if (kk < 4) v = w_ih1[R * 4 + kk];
                        else if (kk < 54) v = w_hh1[R * HID + (kk - 4)];
                    }
                    f[j] = (f16)(v * sc);
                }
                Af[i][kt] = f;
            }
        } else {
#pragma unroll
            for (int kt = 0; kt < 4; ++kt) {
                v8h f;
#pragma unroll
                for (int j = 0; j < 8; ++j) {
                    const int kk = kt * 32 + q * 8 + j;
                    float v = 0.0f;
                    if (rv) {
                        if (kk < HID) v = w_ih2[R * HID + kk];
                        else if (kk >= 64 && kk < 64 + HID) v = w_hh2[R * HID + (kk - 64)];
                    }
                    f[j] = (f16)(v * sc);
                }
                Af[i][kt] = f;
            }
        }
    }

    // ---- bias accumulators (C-in): reg r = gate r, unit = tile*4+q ----
    v4f bias0 = {0.f, 0.f, 0.f, 0.f}, bias1 = {0.f, 0.f, 0.f, 0.f};
#pragma unroll
    for (int r = 0; r < 4; ++r) {
        const float scr = (r == 2) ? (2.0f * LOG2E) : (-LOG2E);
        const int u0 = wa * 4 + q;
        const int u1t = (wa + 8) * 4 + q;
        const float* bi = grpB ? b_ih2 : b_ih1;
        const float* bh = grpB ? b_hh2 : b_hh1;
        if (u0 < HID) bias0[r] = (bi[r * HID + u0] + bh[r * HID + u0]) * scr;
        if ((wa + 8) < NT && u1t < HID)
            bias1[r] = (bi[r * HID + u1t] + bh[r * HID + u1t]) * scr;
    }
    const float wfc_me = (grpB && valid_upd) ? w_fc[u_me] : 0.0f;
    const float bfc = b_fc[0];
    float c_me = 0.0f;                // L1 cell (waves 0-7) / L2 cell (waves 8-15)

    // ---- LDS init + x preload ----
    for (int idx = tid; idx < 2 * BB * S1H; idx += NTHR) ((f16*)u1h)[idx] = (f16)0.0f;
    for (int idx = tid; idx < 4 * SL2; idx += NTHR) ((f16*)u2h)[idx] = (f16)0.0f;
    ((float*)fcw)[tid] = 0.0f;        // 2*8*64 = 1024 == NTHR
    for (int i = tid; i < SEQ * BB; i += NTHR) {   // 4 iters, coalesced
        const int t = i >> 3, b = i & 7;
        const float4 v = *reinterpret_cast<const float4*>(
            x + ((size_t)t * BATCH + bbase + b) * 4);
        f16 p[4] = {(f16)v.x, (f16)v.y, (f16)v.z, (f16)v.w};
        *reinterpret_cast<uint2*>(&xl[t][b * 4]) = *reinterpret_cast<uint2*>(p);
    }
    __syncthreads();
    if (tid < BB) {   // x(0) -> u1 parity 0
        *reinterpret_cast<uint2*>(&u1h[0][tid * S1H]) =
            *reinterpret_cast<const uint2*>(&xl[0][tid * 4]);
    }
    __syncthreads();

    // ---- static wave priority: heavy (2-tile) waves preferred (T5) ----
    if (heavy) __builtin_amdgcn_s_setprio(1);

    // ---- per-lane LDS bases ----
    f16* const u2f = &u2h[0][0];
    const int off_rd2    = b_me * S2H + q * 8;     // L2 C-read base (in slot)
    const int off_w_relu = b_me * S2H + u_me;      // relu_h1 (k=0..49)
    const int off_w_h2   = b_me * S2H + 64 + u_me; // h2 (k=64..113)
    const f16* u1rp[2] = {u1h[0] + b_me * S1H, u1h[1] + b_me * S1H};
    f16* u1wp[2] = {u1h[0] + b_me * S1H, u1h[1] + b_me * S1H};

    // ---- cross-barrier prefetch registers (L2 relu half) ----
    v8h c0f = {}; v8h c1f = {};      // slot 0 relu = zeros at s=0

    // ---- superstep body (pr/pn literal; slot offsets arithmetic) ----
    auto body = [&](int s, int pr, int pn) __attribute__((always_inline)) {
        const int sl_rd = (s & 3) * SL2;          // uniform (SALU)
        const int sl_n1 = ((s + 1) & 3) * SL2;
        const int sl_n2 = ((s + 2) & 3) * SL2;
        if (!grpB) {
            // ---------- L1 gates(t=s) ----------
            const f16* u1r = u1rp[pr];
            const v8h B0 = *reinterpret_cast<const v8h*>(&u1r[q * 8]);
            const v8h B1 = *reinterpret_cast<const v8h*>(&u1r[32 + q * 8]);
            v4f a0 = bias0;
            a0 = MFMA(Af[0][0], B0, a0);
            a0 = MFMA(Af[0][1], B1, a0);
            v4f m = a0;
            if (heavy) {               // wave-uniform; hi lanes pick tile wa+8
                v4f a1 = bias1;
                a1 = MFMA(Af[1][0], B0, a1);
                a1 = MFMA(Af[1][1], B1, a1);
                if (hiHalf) m = a1;
            }
            const float A  = 1.0f + EXP2F(m[0]);
            const float F  = 1.0f + EXP2F(m[1]);
            const float Bv = 1.0f + EXP2F(m[2]);
            const float C  = 1.0f + EXP2F(m[3]);
            const float AB = A * Bv;
            c_me = (c_me * AB + (Bv - 2.0f) * F) * RCPF(F * AB);
            const float D = 1.0f + EXP2F(c_me * (2.0f * LOG2E));
            const float h1v = (D - 2.0f) * RCPF(C * D);
            if (valid_upd) {
                u1wp[pn][4 + u_me] = (f16)h1v;
                u2f[sl_n2 + off_w_relu] = (f16)fmaxf(h1v, 0.0f);
            }
            // ---------- out reduce+store for t=s-3 (light wave 6) ----------
            if (wv == 6 && s >= 3 && s < SEQ + 3) {
                float v = 0.0f;
#pragma unroll
                for (int k2 = 0; k2 < 8; ++k2) v += fcw[pn][k2][lane];
                v += __shfl_xor(v, 8);     // merge lo/hi tile halves (same batch)
                v += __shfl_xor(v, 16);    // merge quads
                v += __shfl_xor(v, 32);
                if (lane < BB) outb[s - 3][lane] = v + bfc;
            }
        } else {
            // ---------- x(s+1) staging: LDS -> LDS (light wave 8) ----------
            if (wv == 8 && lane < BB) {
                const int tn = (s + 1 < SEQ) ? s + 1 : SEQ - 1;
                *reinterpret_cast<uint2*>(&u1h[pn][lane * S1H]) =
                    *reinterpret_cast<const uint2*>(&xl[tn][lane * 4]);
            }
            // ---------- L2 gates(t=s-2): relu half in regs, h2 half fresh ----
            const f16* rd = u2f + sl_rd + off_rd2;
            const v8h C2 = *reinterpret_cast<const v8h*>(rd + 64);
            const v8h C3 = *reinterpret_cast<const v8h*>(rd + 96);
            // prefetch next superstep's relu half (slot s+1: written at s-1,
            // final; its h2 half being written THIS superstep is disjoint)
            const f16* pf = u2f + sl_n1 + off_rd2;
            const v8h nc0 = *reinterpret_cast<const v8h*>(pf);
            const v8h nc1 = *reinterpret_cast<const v8h*>(pf + 32);
            v4f a0 = bias0;                       // chain order == R7
            a0 = MFMA(Af[0][0], c0f, a0);         // regs: starts at barrier exit
            a0 = MFMA(Af[0][1], c1f, a0);
            a0 = MFMA(Af[0][2], C2, a0);          // ds latency hidden above
            a0 = MFMA(Af[0][3], C3, a0);
            v4f m = a0;
            if (heavy) {
                v4f a1 = bias1;
                a1 = MFMA(Af[1][0], c0f, a1);
                a1 = MFMA(Af[1][1], c1f, a1);
                a1 = MFMA(Af[1][2], C2, a1);
                a1 = MFMA(Af[1][3], C3, a1);
                if (hiHalf) m = a1;
            }
            c0f = nc0; c1f = nc1;                 // rotate prefetch regs
            const float A  = 1.0f + EXP2F(m[0]);
            const float F  = 1.0f + EXP2F(m[1]);
            const float Bv = 1.0f + EXP2F(m[2]);
            const float C  = 1.0f + EXP2F(m[3]);
            const float AB = A * Bv;
            const float cn = (c_me * AB + (Bv - 2.0f) * F) * RCPF(F * AB);
            const float D = 1.0f + EXP2F(cn * (2.0f * LOG2E));
            const float h2v = (D - 2.0f) * RCPF(C * D);
            float p = 0.0f;
            if (s >= 2 && s < SEQ + 2) {        // t=s-2 in [0, 511]
                c_me = cn;
                if (valid_upd) u2f[sl_n1 + off_w_h2] = (f16)h2v;
                p = fmaxf(h2v, 0.0f) * wfc_me;  // wfc_me=0 on invalid lanes
            }
            fcw[pr][wv - 8][lane] = p;          // RAW partial, no shfl tail
        }
        __syncthreads();   // the ONE barrier per superstep
    };

    // ---- pipelined supersteps, unrolled x2 (NSTEP = 516 is even) ----
#pragma unroll 1
    for (int s = 0; s < NSTEP; s += 2) {
        body(s, 0, 1);
        body(s + 1, 1, 0);
    }

    // ---- epilogue: flush outb -> global ----
    {
        const int i = tid;                 // SEQ*2 == 1024 == NTHR
        const int t = i >> 1, hb = (i & 1) * 4;
        *reinterpret_cast<float4*>(out + (size_t)t * BATCH + bbase + hb) =
            *reinterpret_cast<const float4*>(&outb[t][hb]);
    }
}

extern "C" void kernel_launch(void* const* d_in, const int* in_sizes, int n_in,
                              void* d_out, int out_size, void* d_ws, size_t ws_size,
                              hipStream_t stream) {
    const float* X    = (const float*)d_in[0];
    const float* Wih1 = (const float*)d_in[1];
    const float* Whh1 = (const float*)d_in[2];
    const float* Bih1 = (const float*)d_in[3];
    const float* Bhh1 = (const float*)d_in[4];
    const float* Wih2 = (const float*)d_in[5];
    const float* Whh2 = (const float*)d_in[6];
    const float* Bih2 = (const float*)d_in[7];
    const float* Bhh2 = (const float*)d_in[8];
    const float* Wfc  = (const float*)d_in[9];
    const float* Bfc  = (const float*)d_in[10];
    float* out = (float*)d_out;

    lstm2_fused<<<dim3(NBLK), dim3(NTHR), 0, stream>>>(
        X, Wih1, Whh1, Bih1, Bhh1, Wih2, Whh2, Bih2, Bhh2, Wfc, Bfc, out);
}